// Round 9
// baseline (592.601 us; speedup 1.0000x reference)
//
#include <hip/hip_runtime.h>
#include <hip/hip_cooperative_groups.h>
#include <hip/hip_bf16.h>
#include <stdint.h>

#define CCH 128
#define BINS 64
#define NCELL (BINS * BINS)
#define MAXPC 1024   // padded perm stride; Poisson(244) max ~320 << 1024

typedef float f32x4 __attribute__((ext_vector_type(4)));
namespace cg = cooperative_groups;

// Single cooperative kernel, 5 phases separated by grid.sync().
// Phases are the proven R8 kernels re-expressed grid-stride.
__global__ void __launch_bounds__(512, 4) k_mega(
        const f32x4* __restrict__ x4, const float2* __restrict__ coords2,
        const float* __restrict__ dwk, const float* __restrict__ dwb,
        const float* __restrict__ pww, const float* __restrict__ pwb,
        const float* __restrict__ lns, const float* __restrict__ lno,
        int n, float4* __restrict__ partials, int* __restrict__ hist,
        int* __restrict__ perm, uint16_t* __restrict__ cell16,
        f32x4* __restrict__ grid4, float* __restrict__ cellvec,
        f32x4* __restrict__ out4)
{
    cg::grid_group gg = cg::this_grid();
    const int t = threadIdx.x;
    const int bid = blockIdx.x;
    const int nblk = gridDim.x;          // 256 or 512, divides NCELL
    const int stride = nblk * 512;
    const int gt = bid * 512 + t;

    __shared__ float w[CCH * CCH];       // 64 KB (phase D)
    __shared__ f32x4 redc[16][32];       // 8 KB  (phase C)
    __shared__ float g[4][CCH];          // 2 KB  (phase D)
    __shared__ float red2[4][CCH];       // 2 KB  (phase D)
    __shared__ float4 wred[8];
    __shared__ float bc[4];

    // ---------- Phase A: zero hist + per-block coord min/max partials ----------
    if (gt < NCELL) hist[gt] = 0;
    {
        float mn0 = INFINITY, mn1 = INFINITY, mx0 = -INFINITY, mx1 = -INFINITY;
        for (int i = gt; i < n; i += stride) {
            float2 c = coords2[i];
            mn0 = fminf(mn0, c.x); mx0 = fmaxf(mx0, c.x);
            mn1 = fminf(mn1, c.y); mx1 = fmaxf(mx1, c.y);
        }
        #pragma unroll
        for (int off = 32; off > 0; off >>= 1) {
            mn0 = fminf(mn0, __shfl_down(mn0, off));
            mn1 = fminf(mn1, __shfl_down(mn1, off));
            mx0 = fmaxf(mx0, __shfl_down(mx0, off));
            mx1 = fmaxf(mx1, __shfl_down(mx1, off));
        }
        if ((t & 63) == 0) wred[t >> 6] = make_float4(mn0, mn1, mx0, mx1);
        __syncthreads();
        if (t == 0) {
            float4 r = wred[0];
            #pragma unroll
            for (int wv = 1; wv < 8; wv++) {
                float4 p = wred[wv];
                r.x = fminf(r.x, p.x); r.y = fminf(r.y, p.y);
                r.z = fmaxf(r.z, p.z); r.w = fmaxf(r.w, p.w);
            }
            partials[bid] = r;
        }
    }
    gg.sync();

    // ---------- Phase B: reduce partials (redundant per block) + cell index ----------
    {
        float mn0 = INFINITY, mn1 = INFINITY, mx0 = -INFINITY, mx1 = -INFINITY;
        if (t < nblk) {
            float4 p = partials[t];
            mn0 = p.x; mn1 = p.y; mx0 = p.z; mx1 = p.w;
        }
        #pragma unroll
        for (int off = 32; off > 0; off >>= 1) {
            mn0 = fminf(mn0, __shfl_down(mn0, off));
            mn1 = fminf(mn1, __shfl_down(mn1, off));
            mx0 = fmaxf(mx0, __shfl_down(mx0, off));
            mx1 = fmaxf(mx1, __shfl_down(mx1, off));
        }
        if ((t & 63) == 0) wred[t >> 6] = make_float4(mn0, mn1, mx0, mx1);
        __syncthreads();
        if (t == 0) {
            float4 r = wred[0];
            #pragma unroll
            for (int wv = 1; wv < 8; wv++) {
                float4 p = wred[wv];
                r.x = fminf(r.x, p.x); r.y = fminf(r.y, p.y);
                r.z = fmaxf(r.z, p.z); r.w = fmaxf(r.w, p.w);
            }
            bc[0] = r.x; bc[1] = r.y; bc[2] = r.z; bc[3] = r.w;
        }
        __syncthreads();
        float cmin0 = bc[0], cmin1 = bc[1];
        float span0 = fmaxf(bc[2] - cmin0, 1e-6f);
        float span1 = fmaxf(bc[3] - cmin1, 1e-6f);
        for (int i = gt; i < n; i += stride) {
            float2 c = coords2[i];
            float n0 = (c.x - cmin0) / span0;
            float n1 = (c.y - cmin1) / span1;
            int g0 = (int)floorf(n0 * 63.0f);
            int g1 = (int)floorf(n1 * 63.0f);
            g0 = min(max(g0, 0), BINS - 1);
            g1 = min(max(g1, 0), BINS - 1);
            int cell = g0 * BINS + g1;
            int rank = atomicAdd(&hist[cell], 1);
            if (rank < MAXPC) perm[(cell << 10) + rank] = i;
            cell16[i] = (uint16_t)cell;
        }
    }
    gg.sync();

    // ---------- Phase C: per-cell segmented sum (16 streams x batch-4) ----------
    {
        int c4 = t & 31;
        int s  = t >> 5;
        int per = NCELL / nblk;
        for (int cc = 0; cc < per; cc++) {
            int cell = bid + cc * nblk;              // unique cover of 0..NCELL
            int cnt = min(hist[cell], MAXPC);
            const int* pr = perm + (cell << 10);
            f32x4 a0 = (f32x4)(0.f), a1 = (f32x4)(0.f), a2 = (f32x4)(0.f), a3 = (f32x4)(0.f);
            int R = cnt >> 6;
            for (int r = 0; r < R; r++) {
                int4 pv = *(const int4*)&pr[(r << 6) + (s << 2)];
                a0 += x4[(long long)pv.x * 32 + c4];
                a1 += x4[(long long)pv.y * 32 + c4];
                a2 += x4[(long long)pv.z * 32 + c4];
                a3 += x4[(long long)pv.w * 32 + c4];
            }
            for (int j = (R << 6) + s; j < cnt; j += 16)
                a0 += x4[(long long)pr[j] * 32 + c4];
            redc[s][c4] = (a0 + a1) + (a2 + a3);
            __syncthreads();
            if (s < 8) redc[s][c4] += redc[s + 8][c4];
            __syncthreads();
            if (s < 4) redc[s][c4] += redc[s + 4][c4];
            __syncthreads();
            if (s < 2) redc[s][c4] += redc[s + 2][c4];
            __syncthreads();
            if (s == 0) grid4[cell * 32 + c4] = redc[0][c4] + redc[1][c4];
            __syncthreads();
        }
    }
    gg.sync();

    // ---------- Phase D: depthwise 3x3 conv + pointwise matmul + LayerNorm ----------
    {
        for (int k = t; k < CCH * CCH / 4; k += 512)
            ((f32x4*)w)[k] = ((const f32x4*)pww)[k];
        __syncthreads();
        const float* grid_f = (const float*)grid4;
        int j  = t & 127;
        int cl = t >> 7;
        int rounds = NCELL / nblk / 4;               // 2 (nblk=512) or 4 (256)
        for (int rr = 0; rr < rounds; rr++) {
            int cell = bid * (rounds * 4) + rr * 4 + cl;
            int gi = cell >> 6, gj = cell & (BINS - 1);
            float acc = dwb[j];
            #pragma unroll
            for (int ki = 0; ki < 3; ki++) {
                int ni = gi + ki - 1;
                if (ni < 0 || ni >= BINS) continue;
                #pragma unroll
                for (int kj = 0; kj < 3; kj++) {
                    int nj = gj + kj - 1;
                    if (nj < 0 || nj >= BINS) continue;
                    acc += grid_f[((ni << 6) + nj) * CCH + j] * dwk[(ki * 3 + kj) * CCH + j];
                }
            }
            g[cl][j] = acc;
            __syncthreads();
            float o = pwb[j];
            #pragma unroll 8
            for (int k = 0; k < CCH; k++) o += g[cl][k] * w[k * CCH + j];
            red2[cl][j] = o;
            __syncthreads();
            #pragma unroll
            for (int sft = 64; sft > 0; sft >>= 1) {
                if (j < sft) red2[cl][j] += red2[cl][j + sft];
                __syncthreads();
            }
            float mu = red2[cl][0] * (1.0f / CCH);
            __syncthreads();
            float d = o - mu;
            red2[cl][j] = d * d;
            __syncthreads();
            #pragma unroll
            for (int sft = 64; sft > 0; sft >>= 1) {
                if (j < sft) red2[cl][j] += red2[cl][j + sft];
                __syncthreads();
            }
            float var = red2[cl][0] * (1.0f / CCH);
            cellvec[cell * CCH + j] = d * rsqrtf(var + 1e-5f) * lns[j] + lno[j];
            __syncthreads();
        }
    }
    gg.sync();

    // ---------- Phase E: out[i] = x[i] + cellvec[cell[i]] ----------
    {
        const f32x4* cellvec4 = (const f32x4*)cellvec;
        long long tot = (long long)n * 32;
        for (long long e = gt; e < tot; e += stride) {
            int p = (int)(e >> 5);
            int q = (int)(e & 31);
            int cell = (int)cell16[p];               // broadcast within half-wave
            f32x4 xv = __builtin_nontemporal_load(&x4[e]);
            f32x4 cv = cellvec4[cell * 32 + q];      // L2-resident (2 MB)
            __builtin_nontemporal_store(xv + cv, &out4[e]);
        }
    }
}

extern "C" void kernel_launch(void* const* d_in, const int* in_sizes, int n_in,
                              void* d_out, int out_size, void* d_ws, size_t ws_size,
                              hipStream_t stream) {
    const f32x4*  x4      = (const f32x4*)d_in[0];
    const float2* coords2 = (const float2*)d_in[1];
    const float*  dwk     = (const float*)d_in[2];
    const float*  dwb     = (const float*)d_in[3];
    const float*  pww     = (const float*)d_in[4];
    const float*  pwb     = (const float*)d_in[5];
    const float*  lns     = (const float*)d_in[6];
    const float*  lno     = (const float*)d_in[7];
    int n = in_sizes[0] / CCH;

    float*    grid     = (float*)d_ws;                      // 2 MB
    float*    cellvec  = grid + NCELL * CCH;                // 2 MB
    float4*   partials = (float4*)(cellvec + NCELL * CCH);  // 8 KB
    int*      hist     = (int*)(partials + 512);            // 16 KB
    int*      perm     = hist + NCELL;                      // 16 MB
    uint16_t* cell16   = (uint16_t*)(perm + NCELL * MAXPC); // 2 MB
    f32x4*    grid4    = (f32x4*)grid;
    f32x4*    out4     = (f32x4*)d_out;

    int occ = 0;
    hipOccupancyMaxActiveBlocksPerMultiprocessor(&occ, (const void*)k_mega, 512, 0);
    int nblk = (occ >= 2) ? 512 : 256;                      // both divide NCELL

    void* args[] = { (void*)&x4, (void*)&coords2, (void*)&dwk, (void*)&dwb,
                     (void*)&pww, (void*)&pwb, (void*)&lns, (void*)&lno,
                     (void*)&n, (void*)&partials, (void*)&hist, (void*)&perm,
                     (void*)&cell16, (void*)&grid4, (void*)&cellvec, (void*)&out4 };
    hipLaunchCooperativeKernel((const void*)k_mega, dim3(nblk), dim3(512),
                               args, 0, stream);
}

// Round 10
// 393.573 us; speedup vs baseline: 1.5057x; 1.5057x over previous
//
#include <hip/hip_runtime.h>
#include <hip/hip_bf16.h>
#include <stdint.h>

#define CCH 128
#define BINS 64
#define NCELL (BINS * BINS)
#define MAXPC 1024   // padded perm stride; Poisson(244) max ~320 << 1024

typedef float f32x4 __attribute__((ext_vector_type(4)));

// K1: per-block min/max partials (no atomics, no sentinels) + zero hist.
__global__ void __launch_bounds__(256) k_minmax(const float2* __restrict__ coords2, int n,
                                                float4* __restrict__ partials,
                                                int* __restrict__ hist) {
    int bid = blockIdx.x, t = threadIdx.x;
    if (t < 4) hist[bid * 4 + t] = 0;          // 1024 blocks x 4 = 4096
    float mn0 = INFINITY, mn1 = INFINITY, mx0 = -INFINITY, mx1 = -INFINITY;
    for (int i = bid * 256 + t; i < n; i += 1024 * 256) {
        float2 c = coords2[i];
        mn0 = fminf(mn0, c.x); mx0 = fmaxf(mx0, c.x);
        mn1 = fminf(mn1, c.y); mx1 = fmaxf(mx1, c.y);
    }
    #pragma unroll
    for (int off = 32; off > 0; off >>= 1) {
        mn0 = fminf(mn0, __shfl_down(mn0, off));
        mn1 = fminf(mn1, __shfl_down(mn1, off));
        mx0 = fmaxf(mx0, __shfl_down(mx0, off));
        mx1 = fmaxf(mx1, __shfl_down(mx1, off));
    }
    __shared__ float4 wred[4];
    if ((t & 63) == 0) wred[t >> 6] = make_float4(mn0, mn1, mx0, mx1);
    __syncthreads();
    if (t == 0) {
        float4 r = wred[0];
        #pragma unroll
        for (int wv = 1; wv < 4; wv++) {
            float4 p = wred[wv];
            r.x = fminf(r.x, p.x); r.y = fminf(r.y, p.y);
            r.z = fmaxf(r.z, p.z); r.w = fmaxf(r.w, p.w);
        }
        partials[bid] = r;
    }
}

// K2: reduce partials inline -> cell index (exact ref op order) -> atomic rank
// -> direct padded-perm write + u16 cell store.
__global__ void __launch_bounds__(256) k_cellidx(const float2* __restrict__ coords2, int n,
        const float4* __restrict__ partials, int* __restrict__ hist,
        int* __restrict__ perm, uint16_t* __restrict__ cell16) {
    int t = threadIdx.x;
    float mn0 = INFINITY, mn1 = INFINITY, mx0 = -INFINITY, mx1 = -INFINITY;
    #pragma unroll
    for (int k = t; k < 1024; k += 256) {
        float4 p = partials[k];
        mn0 = fminf(mn0, p.x); mn1 = fminf(mn1, p.y);
        mx0 = fmaxf(mx0, p.z); mx1 = fmaxf(mx1, p.w);
    }
    #pragma unroll
    for (int off = 32; off > 0; off >>= 1) {
        mn0 = fminf(mn0, __shfl_down(mn0, off));
        mn1 = fminf(mn1, __shfl_down(mn1, off));
        mx0 = fmaxf(mx0, __shfl_down(mx0, off));
        mx1 = fmaxf(mx1, __shfl_down(mx1, off));
    }
    __shared__ float4 wred[4];
    __shared__ float bc[4];
    if ((t & 63) == 0) wred[t >> 6] = make_float4(mn0, mn1, mx0, mx1);
    __syncthreads();
    if (t == 0) {
        float4 r = wred[0];
        #pragma unroll
        for (int wv = 1; wv < 4; wv++) {
            float4 p = wred[wv];
            r.x = fminf(r.x, p.x); r.y = fminf(r.y, p.y);
            r.z = fmaxf(r.z, p.z); r.w = fmaxf(r.w, p.w);
        }
        bc[0] = r.x; bc[1] = r.y; bc[2] = r.z; bc[3] = r.w;
    }
    __syncthreads();
    int i = blockIdx.x * 256 + t;
    if (i >= n) return;
    float2 c = coords2[i];
    float cmin0 = bc[0], cmin1 = bc[1];
    float span0 = fmaxf(bc[2] - cmin0, 1e-6f);
    float span1 = fmaxf(bc[3] - cmin1, 1e-6f);
    float n0 = (c.x - cmin0) / span0;
    float n1 = (c.y - cmin1) / span1;
    int g0 = (int)floorf(n0 * 63.0f);
    int g1 = (int)floorf(n1 * 63.0f);
    g0 = min(max(g0, 0), BINS - 1);
    g1 = min(max(g1, 0), BINS - 1);
    int cell = g0 * BINS + g1;
    int rank = atomicAdd(&hist[cell], 1);
    if (rank < MAXPC) perm[(cell << 10) + rank] = i;
    cell16[i] = (uint16_t)cell;
}

// K3: segmented sum; 16 streams x batch-4; int4 perm loads; plain loads.
__global__ void __launch_bounds__(512) k_cellsum(const f32x4* __restrict__ x4,
                                                 const int* __restrict__ perm,
                                                 const int* __restrict__ hist,
                                                 f32x4* __restrict__ grid4) {
    __shared__ f32x4 red[16][32];
    int cell = blockIdx.x;
    int t = threadIdx.x;
    int c4 = t & 31;
    int s  = t >> 5;                       // 0..15 point streams
    int cnt = min(hist[cell], MAXPC);
    const int* pr = perm + (cell << 10);
    f32x4 a0 = (f32x4)(0.f), a1 = (f32x4)(0.f), a2 = (f32x4)(0.f), a3 = (f32x4)(0.f);
    int R = cnt >> 6;                      // full rounds of 64 points
    for (int r = 0; r < R; r++) {
        int4 pv = *(const int4*)&pr[(r << 6) + (s << 2)];
        a0 += x4[(long long)pv.x * 32 + c4];
        a1 += x4[(long long)pv.y * 32 + c4];
        a2 += x4[(long long)pv.z * 32 + c4];
        a3 += x4[(long long)pv.w * 32 + c4];
    }
    for (int j = (R << 6) + s; j < cnt; j += 16)
        a0 += x4[(long long)pr[j] * 32 + c4];
    red[s][c4] = (a0 + a1) + (a2 + a3);
    __syncthreads();
    if (s < 8) red[s][c4] += red[s + 8][c4];
    __syncthreads();
    if (s < 4) red[s][c4] += red[s + 4][c4];
    __syncthreads();
    if (s < 2) red[s][c4] += red[s + 2][c4];
    __syncthreads();
    if (s == 0) grid4[cell * 32 + c4] = red[0][c4] + red[1][c4];
}

// K4: fused depthwise 3x3 conv + pointwise matmul + LayerNorm.
// 4 cells per block; pw_w read directly from L2 (no LDS staging -> 4 KB LDS,
// all 1024 blocks co-resident at 4/CU instead of 2 sequential waves-of-blocks).
__global__ void __launch_bounds__(512) k_convpwln(const float* __restrict__ grid,
        const float* __restrict__ dwk, const float* __restrict__ dwb,
        const float* __restrict__ pww, const float* __restrict__ pwb,
        const float* __restrict__ lns, const float* __restrict__ lno,
        float* __restrict__ cellvec) {
    __shared__ float g[4][CCH];
    __shared__ float red[4][CCH];
    int t = threadIdx.x;
    int j  = t & 127;
    int cl = t >> 7;                       // 0..3, uniform per wave
    int cell = blockIdx.x * 4 + cl;

    int gi = cell >> 6, gj = cell & (BINS - 1);
    float acc = dwb[j];
    #pragma unroll
    for (int ki = 0; ki < 3; ki++) {
        int ni = gi + ki - 1;
        if (ni < 0 || ni >= BINS) continue;
        #pragma unroll
        for (int kj = 0; kj < 3; kj++) {
            int nj = gj + kj - 1;
            if (nj < 0 || nj >= BINS) continue;
            acc += grid[((ni << 6) + nj) * CCH + j] * dwk[(ki * 3 + kj) * CCH + j];
        }
    }
    g[cl][j] = acc;
    __syncthreads();

    float o = pwb[j];
    #pragma unroll 8
    for (int k = 0; k < CCH; k++) o += g[cl][k] * pww[k * CCH + j];

    red[cl][j] = o;
    __syncthreads();
    #pragma unroll
    for (int sft = 64; sft > 0; sft >>= 1) {
        if (j < sft) red[cl][j] += red[cl][j + sft];
        __syncthreads();
    }
    float mu = red[cl][0] * (1.0f / CCH);
    __syncthreads();
    float d = o - mu;
    red[cl][j] = d * d;
    __syncthreads();
    #pragma unroll
    for (int sft = 64; sft > 0; sft >>= 1) {
        if (j < sft) red[cl][j] += red[cl][j + sft];
        __syncthreads();
    }
    float var = red[cl][0] * (1.0f / CCH);
    cellvec[cell * CCH + j] = d * rsqrtf(var + 1e-5f) * lns[j] + lno[j];
}

// K5: out[i] = x[i] + cellvec[cell[i]]. Grid-stride, 4 independent
// load->gather->store chains per thread; per-instruction mapping is the
// proven lane-contiguous f32x4 (1 KiB/wave/instr).
__global__ void __launch_bounds__(256) k_final(const f32x4* __restrict__ x4,
        const uint16_t* __restrict__ cell16, const f32x4* __restrict__ cellvec4,
        int n, f32x4* __restrict__ out4) {
    const int tot = n * 32;                     // 32e6 < 2^31
    const int stride = gridDim.x * 256;         // 4096*256 = 1,048,576
    int e = blockIdx.x * 256 + threadIdx.x;
    for (; e + 3 * stride < tot; e += 4 * stride) {
        int e0 = e, e1 = e + stride, e2 = e + 2 * stride, e3 = e + 3 * stride;
        int c0 = (int)cell16[e0 >> 5];
        int c1 = (int)cell16[e1 >> 5];
        int c2 = (int)cell16[e2 >> 5];
        int c3 = (int)cell16[e3 >> 5];
        f32x4 x0 = __builtin_nontemporal_load(&x4[e0]);
        f32x4 x1 = __builtin_nontemporal_load(&x4[e1]);
        f32x4 x2 = __builtin_nontemporal_load(&x4[e2]);
        f32x4 x3 = __builtin_nontemporal_load(&x4[e3]);
        f32x4 v0 = cellvec4[c0 * 32 + (e0 & 31)];
        f32x4 v1 = cellvec4[c1 * 32 + (e1 & 31)];
        f32x4 v2 = cellvec4[c2 * 32 + (e2 & 31)];
        f32x4 v3 = cellvec4[c3 * 32 + (e3 & 31)];
        __builtin_nontemporal_store(x0 + v0, &out4[e0]);
        __builtin_nontemporal_store(x1 + v1, &out4[e1]);
        __builtin_nontemporal_store(x2 + v2, &out4[e2]);
        __builtin_nontemporal_store(x3 + v3, &out4[e3]);
    }
    for (; e < tot; e += stride) {
        int cell = (int)cell16[e >> 5];
        f32x4 xv = __builtin_nontemporal_load(&x4[e]);
        f32x4 cv = cellvec4[cell * 32 + (e & 31)];
        __builtin_nontemporal_store(xv + cv, &out4[e]);
    }
}

extern "C" void kernel_launch(void* const* d_in, const int* in_sizes, int n_in,
                              void* d_out, int out_size, void* d_ws, size_t ws_size,
                              hipStream_t stream) {
    const float* x      = (const float*)d_in[0];
    const float* coords = (const float*)d_in[1];
    const float* dwk    = (const float*)d_in[2];
    const float* dwb    = (const float*)d_in[3];
    const float* pww    = (const float*)d_in[4];
    const float* pwb    = (const float*)d_in[5];
    const float* lns    = (const float*)d_in[6];
    const float* lno    = (const float*)d_in[7];
    int n = in_sizes[0] / CCH;

    float*    grid     = (float*)d_ws;                 // 2 MB
    float*    cellvec  = grid + NCELL * CCH;           // 2 MB
    float4*   partials = (float4*)(cellvec + NCELL * CCH); // 16 KB
    int*      hist     = (int*)(partials + 1024);      // 16 KB
    int*      perm     = hist + NCELL;                 // NCELL*MAXPC ints = 16 MB
    uint16_t* cell16   = (uint16_t*)(perm + NCELL * MAXPC); // 2 MB

    k_minmax<<<1024, 256, 0, stream>>>((const float2*)coords, n, partials, hist);
    k_cellidx<<<(n + 255) / 256, 256, 0, stream>>>((const float2*)coords, n, partials, hist, perm, cell16);
    k_cellsum<<<NCELL, 512, 0, stream>>>((const f32x4*)x, perm, hist, (f32x4*)grid);
    k_convpwln<<<NCELL / 4, 512, 0, stream>>>(grid, dwk, dwb, pww, pwb, lns, lno, cellvec);
    k_final<<<4096, 256, 0, stream>>>((const f32x4*)x, cell16, (const f32x4*)cellvec, n, (f32x4*)d_out);
}

// Round 11
// 359.995 us; speedup vs baseline: 1.6461x; 1.0933x over previous
//
#include <hip/hip_runtime.h>
#include <hip/hip_bf16.h>
#include <stdint.h>

#define CCH 128
#define BINS 64
#define NCELL (BINS * BINS)
#define MAXPC 1024   // padded perm stride; Poisson(244) max ~320 << 1024

typedef float f32x4 __attribute__((ext_vector_type(4)));

// K1: per-block min/max partials (no atomics, no sentinels) + zero hist.
__global__ void __launch_bounds__(256) k_minmax(const float2* __restrict__ coords2, int n,
                                                float4* __restrict__ partials,
                                                int* __restrict__ hist) {
    int bid = blockIdx.x, t = threadIdx.x;
    if (t < 4) hist[bid * 4 + t] = 0;          // 1024 blocks x 4 = 4096
    float mn0 = INFINITY, mn1 = INFINITY, mx0 = -INFINITY, mx1 = -INFINITY;
    for (int i = bid * 256 + t; i < n; i += 1024 * 256) {
        float2 c = coords2[i];
        mn0 = fminf(mn0, c.x); mx0 = fmaxf(mx0, c.x);
        mn1 = fminf(mn1, c.y); mx1 = fmaxf(mx1, c.y);
    }
    #pragma unroll
    for (int off = 32; off > 0; off >>= 1) {
        mn0 = fminf(mn0, __shfl_down(mn0, off));
        mn1 = fminf(mn1, __shfl_down(mn1, off));
        mx0 = fmaxf(mx0, __shfl_down(mx0, off));
        mx1 = fmaxf(mx1, __shfl_down(mx1, off));
    }
    __shared__ float4 wred[4];
    if ((t & 63) == 0) wred[t >> 6] = make_float4(mn0, mn1, mx0, mx1);
    __syncthreads();
    if (t == 0) {
        float4 r = wred[0];
        #pragma unroll
        for (int wv = 1; wv < 4; wv++) {
            float4 p = wred[wv];
            r.x = fminf(r.x, p.x); r.y = fminf(r.y, p.y);
            r.z = fmaxf(r.z, p.z); r.w = fmaxf(r.w, p.w);
        }
        partials[bid] = r;
    }
}

// K2: reduce partials inline -> cell index (exact ref op order) -> atomic rank
// -> direct padded-perm write + u16 cell store.
__global__ void __launch_bounds__(256) k_cellidx(const float2* __restrict__ coords2, int n,
        const float4* __restrict__ partials, int* __restrict__ hist,
        int* __restrict__ perm, uint16_t* __restrict__ cell16) {
    int t = threadIdx.x;
    float mn0 = INFINITY, mn1 = INFINITY, mx0 = -INFINITY, mx1 = -INFINITY;
    #pragma unroll
    for (int k = t; k < 1024; k += 256) {
        float4 p = partials[k];
        mn0 = fminf(mn0, p.x); mn1 = fminf(mn1, p.y);
        mx0 = fmaxf(mx0, p.z); mx1 = fmaxf(mx1, p.w);
    }
    #pragma unroll
    for (int off = 32; off > 0; off >>= 1) {
        mn0 = fminf(mn0, __shfl_down(mn0, off));
        mn1 = fminf(mn1, __shfl_down(mn1, off));
        mx0 = fmaxf(mx0, __shfl_down(mx0, off));
        mx1 = fmaxf(mx1, __shfl_down(mx1, off));
    }
    __shared__ float4 wred[4];
    __shared__ float bc[4];
    if ((t & 63) == 0) wred[t >> 6] = make_float4(mn0, mn1, mx0, mx1);
    __syncthreads();
    if (t == 0) {
        float4 r = wred[0];
        #pragma unroll
        for (int wv = 1; wv < 4; wv++) {
            float4 p = wred[wv];
            r.x = fminf(r.x, p.x); r.y = fminf(r.y, p.y);
            r.z = fmaxf(r.z, p.z); r.w = fmaxf(r.w, p.w);
        }
        bc[0] = r.x; bc[1] = r.y; bc[2] = r.z; bc[3] = r.w;
    }
    __syncthreads();
    int i = blockIdx.x * 256 + t;
    if (i >= n) return;
    float2 c = coords2[i];
    float cmin0 = bc[0], cmin1 = bc[1];
    float span0 = fmaxf(bc[2] - cmin0, 1e-6f);
    float span1 = fmaxf(bc[3] - cmin1, 1e-6f);
    float n0 = (c.x - cmin0) / span0;
    float n1 = (c.y - cmin1) / span1;
    int g0 = (int)floorf(n0 * 63.0f);
    int g1 = (int)floorf(n1 * 63.0f);
    g0 = min(max(g0, 0), BINS - 1);
    g1 = min(max(g1, 0), BINS - 1);
    int cell = g0 * BINS + g1;
    int rank = atomicAdd(&hist[cell], 1);
    if (rank < MAXPC) perm[(cell << 10) + rank] = i;
    cell16[i] = (uint16_t)cell;
}

// K3: segmented sum; 16 streams x batch-4; int4 perm loads; plain loads.
__global__ void __launch_bounds__(512) k_cellsum(const f32x4* __restrict__ x4,
                                                 const int* __restrict__ perm,
                                                 const int* __restrict__ hist,
                                                 f32x4* __restrict__ grid4) {
    __shared__ f32x4 red[16][32];
    int cell = blockIdx.x;
    int t = threadIdx.x;
    int c4 = t & 31;
    int s  = t >> 5;                       // 0..15 point streams
    int cnt = min(hist[cell], MAXPC);
    const int* pr = perm + (cell << 10);
    f32x4 a0 = (f32x4)(0.f), a1 = (f32x4)(0.f), a2 = (f32x4)(0.f), a3 = (f32x4)(0.f);
    int R = cnt >> 6;                      // full rounds of 64 points
    for (int r = 0; r < R; r++) {
        int4 pv = *(const int4*)&pr[(r << 6) + (s << 2)];
        a0 += x4[(long long)pv.x * 32 + c4];
        a1 += x4[(long long)pv.y * 32 + c4];
        a2 += x4[(long long)pv.z * 32 + c4];
        a3 += x4[(long long)pv.w * 32 + c4];
    }
    for (int j = (R << 6) + s; j < cnt; j += 16)
        a0 += x4[(long long)pr[j] * 32 + c4];
    red[s][c4] = (a0 + a1) + (a2 + a3);
    __syncthreads();
    if (s < 8) red[s][c4] += red[s + 8][c4];
    __syncthreads();
    if (s < 4) red[s][c4] += red[s + 4][c4];
    __syncthreads();
    if (s < 2) red[s][c4] += red[s + 2][c4];
    __syncthreads();
    if (s == 0) grid4[cell * 32 + c4] = red[0][c4] + red[1][c4];
}

// K4: fused depthwise 3x3 conv + pointwise matmul + LayerNorm.
// 4 cells per block; pw_w read from L2 (no LDS staging; 4 KB LDS, 4 blocks/CU).
__global__ void __launch_bounds__(512) k_convpwln(const float* __restrict__ grid,
        const float* __restrict__ dwk, const float* __restrict__ dwb,
        const float* __restrict__ pww, const float* __restrict__ pwb,
        const float* __restrict__ lns, const float* __restrict__ lno,
        float* __restrict__ cellvec) {
    __shared__ float g[4][CCH];
    __shared__ float red[4][CCH];
    int t = threadIdx.x;
    int j  = t & 127;
    int cl = t >> 7;                       // 0..3, uniform per wave
    int cell = blockIdx.x * 4 + cl;

    int gi = cell >> 6, gj = cell & (BINS - 1);
    float acc = dwb[j];
    #pragma unroll
    for (int ki = 0; ki < 3; ki++) {
        int ni = gi + ki - 1;
        if (ni < 0 || ni >= BINS) continue;
        #pragma unroll
        for (int kj = 0; kj < 3; kj++) {
            int nj = gj + kj - 1;
            if (nj < 0 || nj >= BINS) continue;
            acc += grid[((ni << 6) + nj) * CCH + j] * dwk[(ki * 3 + kj) * CCH + j];
        }
    }
    g[cl][j] = acc;
    __syncthreads();

    float o = pwb[j];
    #pragma unroll 8
    for (int k = 0; k < CCH; k++) o += g[cl][k] * pww[k * CCH + j];

    red[cl][j] = o;
    __syncthreads();
    #pragma unroll
    for (int sft = 64; sft > 0; sft >>= 1) {
        if (j < sft) red[cl][j] += red[cl][j + sft];
        __syncthreads();
    }
    float mu = red[cl][0] * (1.0f / CCH);
    __syncthreads();
    float d = o - mu;
    red[cl][j] = d * d;
    __syncthreads();
    #pragma unroll
    for (int sft = 64; sft > 0; sft >>= 1) {
        if (j < sft) red[cl][j] += red[cl][j + sft];
        __syncthreads();
    }
    float var = red[cl][0] * (1.0f / CCH);
    cellvec[cell * CCH + j] = d * rsqrtf(var + 1e-5f) * lns[j] + lno[j];
}

// K5: out[i] = x[i] + cellvec[cell[i]]. Exact R8 form: one f32x4 per thread,
// 32M threads, consecutive blocks = consecutive addresses (best DRAM locality).
__global__ void __launch_bounds__(256) k_final(const f32x4* __restrict__ x4,
        const uint16_t* __restrict__ cell16, const f32x4* __restrict__ cellvec4,
        int n, f32x4* __restrict__ out4) {
    long long t = (long long)blockIdx.x * 256 + threadIdx.x;
    int p = (int)(t >> 5);
    int q = (int)(t & 31);
    if (p >= n) return;
    int cell = (int)cell16[p];              // 32 same-address lanes -> broadcast
    long long base = (long long)p * 32 + q;
    f32x4 xv = __builtin_nontemporal_load(&x4[base]);
    f32x4 cv = cellvec4[cell * 32 + q];     // L2-resident (2 MB)
    __builtin_nontemporal_store(xv + cv, &out4[base]);
}

extern "C" void kernel_launch(void* const* d_in, const int* in_sizes, int n_in,
                              void* d_out, int out_size, void* d_ws, size_t ws_size,
                              hipStream_t stream) {
    const float* x      = (const float*)d_in[0];
    const float* coords = (const float*)d_in[1];
    const float* dwk    = (const float*)d_in[2];
    const float* dwb    = (const float*)d_in[3];
    const float* pww    = (const float*)d_in[4];
    const float* pwb    = (const float*)d_in[5];
    const float* lns    = (const float*)d_in[6];
    const float* lno    = (const float*)d_in[7];
    int n = in_sizes[0] / CCH;

    float*    grid     = (float*)d_ws;                 // 2 MB
    float*    cellvec  = grid + NCELL * CCH;           // 2 MB
    float4*   partials = (float4*)(cellvec + NCELL * CCH); // 16 KB
    int*      hist     = (int*)(partials + 1024);      // 16 KB
    int*      perm     = hist + NCELL;                 // NCELL*MAXPC ints = 16 MB
    uint16_t* cell16   = (uint16_t*)(perm + NCELL * MAXPC); // 2 MB

    k_minmax<<<1024, 256, 0, stream>>>((const float2*)coords, n, partials, hist);
    k_cellidx<<<(n + 255) / 256, 256, 0, stream>>>((const float2*)coords, n, partials, hist, perm, cell16);
    k_cellsum<<<NCELL, 512, 0, stream>>>((const f32x4*)x, perm, hist, (f32x4*)grid);
    k_convpwln<<<NCELL / 4, 512, 0, stream>>>(grid, dwk, dwb, pww, pwb, lns, lno, cellvec);

    long long tot = (long long)n * 32;
    int blocks = (int)((tot + 255) / 256);
    k_final<<<blocks, 256, 0, stream>>>((const f32x4*)x, cell16, (const f32x4*)cellvec, n, (f32x4*)d_out);
}